// Round 3
// baseline (1073.204 us; speedup 1.0000x reference)
//
#include <hip/hip_runtime.h>
#include <math.h>

// Problem constants
#define NBOX 512
#define BATCH 16
#define TT 32
#define FEAT 2048
#define NCLS 80
#define CTXD 1024
#define FCD 1024
#define HID 1024
#define IN_DIM 3152     // FEAT + NCLS + CTXD
#define G4 4096         // 4*HID

// ---------------------------------------------------------------------------
// Kernel 1: build x = concat([box_feats, boxes_ext[:,5:], ctx_rep], dim=1)
// ---------------------------------------------------------------------------
__global__ void build_x(const float* __restrict__ boxes_ext,
                        const float* __restrict__ box_feats,
                        const float* __restrict__ spatial_ctx,
                        const int* __restrict__ box_im_ids,
                        float* __restrict__ x)
{
    int idx = blockIdx.x * blockDim.x + threadIdx.x;
    const int total = NBOX * IN_DIM;
    for (; idx < total; idx += gridDim.x * blockDim.x) {
        int n = idx / IN_DIM;
        int k = idx - n * IN_DIM;
        float v;
        if (k < FEAT) {
            v = box_feats[n * FEAT + k];
        } else if (k < FEAT + NCLS) {
            v = boxes_ext[n * 85 + 5 + (k - FEAT)];
        } else {
            v = spatial_ctx[box_im_ids[n] * CTXD + (k - FEAT - NCLS)];
        }
        x[idx] = v;
    }
}

// ---------------------------------------------------------------------------
// Kernel 2: transpose w_hh (both dirs) into k-major layout wPT[dir][k][4096]
// so the step kernel's weight loads are coalesced. Runs AFTER reduce_emb so
// its output region can overlap x/part (lifetime disjoint).
// ---------------------------------------------------------------------------
__global__ void transpose_whh(const float* __restrict__ wf,
                              const float* __restrict__ wr,
                              float* __restrict__ wt)
{
    __shared__ float tile[64][65];
    const int dir = blockIdx.z;
    const float* w = dir ? wr : wf;
    float* o = wt + ((size_t)dir << 22);       // dir*1024*4096
    const int kb = blockIdx.x * 64;            // k tile (0..1023)
    const int cb = blockIdx.y * 64;            // col tile (0..4095)
    const int t = threadIdx.x;                 // 256
    const int c0 = t & 63;
    const int r0 = t >> 6;                     // 0..3
#pragma unroll
    for (int i = 0; i < 16; ++i) {
        int r = r0 * 16 + i;
        tile[c0][r] = w[(size_t)(cb + r) * 1024 + kb + c0];   // coalesced in k
    }
    __syncthreads();
#pragma unroll
    for (int i = 0; i < 16; ++i) {
        int k = r0 * 16 + i;
        o[(size_t)(kb + k) * 4096 + cb + c0] = tile[k][c0];   // coalesced in col
    }
}

// ---------------------------------------------------------------------------
// Kernel 3: emb GEMM, K-split partials. C_part[kz] = x[:, kz-chunk] @ w_fc^T
// 64x64 tile, single 64-thread wave, 8x8 micro-tile, BK=8, prefetch.
// Grid (8, 16, 8). K chunks: 7*400 + 352 (both divisible by 8 -> no tail).
// ---------------------------------------------------------------------------
__global__ __launch_bounds__(64) void gemm_emb_part(
    const float* __restrict__ A,   // x [512][3152]
    const float* __restrict__ Bm,  // w_fc [1024][3152]
    float* __restrict__ part)      // [8][512][1024]
{
    __shared__ float As[8][68];
    __shared__ float Bs[8][68];
    const int bm = blockIdx.x * 64;
    const int bn = blockIdx.y * 64;
    const int kz = blockIdx.z;
    const int kbeg = kz * 400;
    int kend = kbeg + 400; if (kend > IN_DIM) kend = IN_DIM;
    const int t = threadIdx.x;
    const int tx = t & 7;
    const int ty = t >> 3;
    float acc[8][8] = {};

    float4 pa0, pa1, pb0, pb1;
    auto loadT = [&](int kk) {
        const float* ap = A + (size_t)(bm + t) * IN_DIM + kk;
        pa0 = *(const float4*)ap; pa1 = *(const float4*)(ap + 4);
        const float* bp = Bm + (size_t)(bn + t) * IN_DIM + kk;
        pb0 = *(const float4*)bp; pb1 = *(const float4*)(bp + 4);
    };
    loadT(kbeg);
    for (int k0 = kbeg; k0 < kend; k0 += 8) {
        As[0][t] = pa0.x; As[1][t] = pa0.y; As[2][t] = pa0.z; As[3][t] = pa0.w;
        As[4][t] = pa1.x; As[5][t] = pa1.y; As[6][t] = pa1.z; As[7][t] = pa1.w;
        Bs[0][t] = pb0.x; Bs[1][t] = pb0.y; Bs[2][t] = pb0.z; Bs[3][t] = pb0.w;
        Bs[4][t] = pb1.x; Bs[5][t] = pb1.y; Bs[6][t] = pb1.z; Bs[7][t] = pb1.w;
        __syncthreads();
        if (k0 + 8 < kend) loadT(k0 + 8);   // prefetch next tile
#pragma unroll
        for (int k = 0; k < 8; ++k) {
            float ar[8], br[8];
            *(float4*)&ar[0] = *(const float4*)&As[k][ty * 4];
            *(float4*)&ar[4] = *(const float4*)&As[k][32 + ty * 4];
            *(float4*)&br[0] = *(const float4*)&Bs[k][tx * 4];
            *(float4*)&br[4] = *(const float4*)&Bs[k][32 + tx * 4];
#pragma unroll
            for (int i = 0; i < 8; ++i)
#pragma unroll
                for (int j = 0; j < 8; ++j)
                    acc[i][j] = fmaf(ar[i], br[j], acc[i][j]);
        }
        __syncthreads();
    }
    float* Cp = part + (size_t)kz * (NBOX * FCD);
#pragma unroll
    for (int i = 0; i < 8; ++i) {
        int row = bm + ty * 4 + (i & 3) + (i >> 2) * 32;
#pragma unroll
        for (int jh = 0; jh < 2; ++jh) {
            int col = bn + jh * 32 + tx * 4;
            float4 v = make_float4(acc[i][jh * 4 + 0], acc[i][jh * 4 + 1],
                                   acc[i][jh * 4 + 2], acc[i][jh * 4 + 3]);
            *(float4*)(Cp + (size_t)row * FCD + col) = v;
        }
    }
}

// Reduce K-split partials + bias + relu -> emb (written into d_out region)
__global__ void reduce_emb(const float* __restrict__ part,
                           const float* __restrict__ bias,
                           float* __restrict__ emb)
{
    int i = blockIdx.x * blockDim.x + threadIdx.x;
    if (i >= NBOX * FCD) return;
    float s = 0.f;
#pragma unroll
    for (int z = 0; z < 8; ++z) s += part[(size_t)z * (NBOX * FCD) + i];
    s += bias[i & (FCD - 1)];
    emb[i] = fmaxf(s, 0.f);
}

// ---------------------------------------------------------------------------
// Kernel 4: xg = emb @ w_ih^T + b_ih + b_hh for both dirs.
// Same single-wave 64x64 skeleton, K=1024. Grid (8, 128): y covers 8192 cols.
// ---------------------------------------------------------------------------
__global__ __launch_bounds__(64) void gemm_xg(
    const float* __restrict__ A,   // emb [512][1024]
    const float* __restrict__ Bf, const float* __restrict__ Br,
    const float* __restrict__ bif, const float* __restrict__ bhf,
    const float* __restrict__ bir, const float* __restrict__ bhr,
    float* __restrict__ xg)        // [2][512][4096]
{
    __shared__ float As[8][68];
    __shared__ float Bs[8][68];
    const int bm = blockIdx.x * 64;
    const int gn = blockIdx.y * 64;
    const int dir = gn >> 12;
    const int bn = gn & 4095;
    const float* Bm = dir ? Br : Bf;
    const float* b1 = dir ? bir : bif;
    const float* b2 = dir ? bhr : bhf;
    float* C = xg + ((size_t)dir << 21);   // 512*4096
    const int t = threadIdx.x;
    const int tx = t & 7;
    const int ty = t >> 3;
    float acc[8][8] = {};

    float4 pa0, pa1, pb0, pb1;
    auto loadT = [&](int kk) {
        const float* ap = A + (size_t)(bm + t) * FCD + kk;
        pa0 = *(const float4*)ap; pa1 = *(const float4*)(ap + 4);
        const float* bp = Bm + (size_t)(bn + t) * FCD + kk;
        pb0 = *(const float4*)bp; pb1 = *(const float4*)(bp + 4);
    };
    loadT(0);
    for (int k0 = 0; k0 < 1024; k0 += 8) {
        As[0][t] = pa0.x; As[1][t] = pa0.y; As[2][t] = pa0.z; As[3][t] = pa0.w;
        As[4][t] = pa1.x; As[5][t] = pa1.y; As[6][t] = pa1.z; As[7][t] = pa1.w;
        Bs[0][t] = pb0.x; Bs[1][t] = pb0.y; Bs[2][t] = pb0.z; Bs[3][t] = pb0.w;
        Bs[4][t] = pb1.x; Bs[5][t] = pb1.y; Bs[6][t] = pb1.z; Bs[7][t] = pb1.w;
        __syncthreads();
        if (k0 + 8 < 1024) loadT(k0 + 8);
#pragma unroll
        for (int k = 0; k < 8; ++k) {
            float ar[8], br[8];
            *(float4*)&ar[0] = *(const float4*)&As[k][ty * 4];
            *(float4*)&ar[4] = *(const float4*)&As[k][32 + ty * 4];
            *(float4*)&br[0] = *(const float4*)&Bs[k][tx * 4];
            *(float4*)&br[4] = *(const float4*)&Bs[k][32 + tx * 4];
#pragma unroll
            for (int i = 0; i < 8; ++i)
#pragma unroll
                for (int j = 0; j < 8; ++j)
                    acc[i][j] = fmaf(ar[i], br[j], acc[i][j]);
        }
        __syncthreads();
    }
#pragma unroll
    for (int jh = 0; jh < 2; ++jh) {
        int col = bn + jh * 32 + tx * 4;
        float4 b1v = *(const float4*)&b1[col];
        float4 b2v = *(const float4*)&b2[col];
#pragma unroll
        for (int i = 0; i < 8; ++i) {
            int row = bm + ty * 4 + (i & 3) + (i >> 2) * 32;
            float4 v;
            v.x = acc[i][jh * 4 + 0] + b1v.x + b2v.x;
            v.y = acc[i][jh * 4 + 1] + b1v.y + b2v.y;
            v.z = acc[i][jh * 4 + 2] + b1v.z + b2v.z;
            v.w = acc[i][jh * 4 + 3] + b1v.w + b2v.w;
            *(float4*)(C + (size_t)row * G4 + col) = v;
        }
    }
}

// ---------------------------------------------------------------------------
// Kernel 5: one LSTM timestep, both directions. 256 blocks (dir x 128),
// block owns 8 hidden units (32 gate cols), all 16 batches, full K=1024.
// h stored transposed [dir][j][b] (double-buffered across steps to avoid the
// fast-block-overwrites-while-slow-block-reads race). c/hsum owner-exclusive.
// ---------------------------------------------------------------------------
__global__ __launch_bounds__(256) void lstm_step(
    const float* __restrict__ wPT,   // [2][1024][4096] k-major
    const float* __restrict__ xg,    // [2][512][4096]
    const float* __restrict__ hin,   // [2][1024][16]
    float* __restrict__ hout,        // [2][1024][16]
    float* __restrict__ c_T,         // [2][1024][16]
    float* __restrict__ hsum,        // [2][1024][16]
    int step)
{
    __shared__ float red[16][33][20];   // [slice][gatecol 0..31][batch]
    const int dir = blockIdx.x >> 7;
    const int hb  = (blockIdx.x & 127) * 8;
    const int t = threadIdx.x;
    const int bg = t & 3;           // batch quad: b = bg*4..+3
    const int cq = (t >> 2) & 3;    // gate index 0..3 (i,f,g,o)
    const int s  = t >> 4;          // k slice: [s*64, s*64+64)

    const float* wk = wPT + ((size_t)dir << 22) + (size_t)(s * 64) * G4 + cq * 1024 + hb;
    const float* hk = hin + (dir << 14) + (s * 64) * BATCH + bg * 4;

    float acc[4][8] = {};
#pragma unroll 4
    for (int ii = 0; ii < 64; ++ii) {
        float4 h4 = *(const float4*)hk;
        float4 wa = *(const float4*)wk;
        float4 wb = *(const float4*)(wk + 4);
        float hr[4] = {h4.x, h4.y, h4.z, h4.w};
        float wr[8] = {wa.x, wa.y, wa.z, wa.w, wb.x, wb.y, wb.z, wb.w};
#pragma unroll
        for (int bi = 0; bi < 4; ++bi)
#pragma unroll
            for (int ci = 0; ci < 8; ++ci)
                acc[bi][ci] = fmaf(hr[bi], wr[ci], acc[bi][ci]);
        hk += BATCH;
        wk += G4;
    }
#pragma unroll
    for (int ci = 0; ci < 8; ++ci)
        *(float4*)&red[s][cq * 8 + ci][bg * 4] =
            make_float4(acc[0][ci], acc[1][ci], acc[2][ci], acc[3][ci]);
    __syncthreads();

    if (t < 128) {
        const int jl = t >> 4;     // hidden-local 0..7
        const int b  = t & 15;
        float g[4];
#pragma unroll
        for (int gi = 0; gi < 4; ++gi) {
            float sum = 0.f;
#pragma unroll
            for (int ss = 0; ss < 16; ++ss) sum += red[ss][gi * 8 + jl][b];
            g[gi] = sum;
        }
        const int tstep = dir ? (TT - 1 - step) : step;
        const int n = b * TT + tstep;
        const float* xgp = xg + ((size_t)dir << 21) + (size_t)n * G4 + hb + jl;
        float pi = g[0] + xgp[0];
        float pf = g[1] + xgp[1024];
        float pg = g[2] + xgp[2048];
        float po = g[3] + xgp[3072];
        const int idx = (dir << 14) + (hb + jl) * BATCH + b;
        float co = c_T[idx];
        float si = 1.f / (1.f + __expf(-pi));
        float sf = 1.f / (1.f + __expf(-pf));
        float so = 1.f / (1.f + __expf(-po));
        float cn = sf * co + si * tanhf(pg);
        float hn = so * tanhf(cn);
        c_T[idx]  = cn;
        hout[idx] = hn;
        hsum[idx] += hn;
    }
}

// ---------------------------------------------------------------------------
// Kernel 6: object_context = hsum / T, reordered to [b][dir*H + j]
// ---------------------------------------------------------------------------
__global__ void finalize_ctx(const float* __restrict__ hsum, float* __restrict__ out)
{
    int i = blockIdx.x * blockDim.x + threadIdx.x;   // 32768
    if (i >= BATCH * 2 * HID) return;
    int b = i >> 11;
    int dir = (i >> 10) & 1;
    int j = i & 1023;
    out[i] = hsum[(dir << 14) + (j << 4) + b] * (1.0f / TT);
}

// ---------------------------------------------------------------------------
// Workspace plan (floats), total ~51 MB:
//   region A (8,388,608 floats = 32 MB), time-shared:
//     phase 1: x @ A+0 (1,613,824), part @ A+1,613,824 (4,194,304)  [23.2 MB]
//     phase 2 (after reduce_emb): wPT = A  (2*1024*4096)            [32 MB]
//   xg   @ ws+8,388,608  (4,194,304)
//   h_T  @ ws+12,582,912 (2 phases * 32,768)
//   c_T  @ +65,536 (32,768);  hsum @ +32,768 (32,768)
// ---------------------------------------------------------------------------
extern "C" void kernel_launch(void* const* d_in, const int* in_sizes, int n_in,
                              void* d_out, int out_size, void* d_ws, size_t ws_size,
                              hipStream_t stream)
{
    const float* boxes_ext   = (const float*)d_in[0];
    const float* box_feats   = (const float*)d_in[1];
    const float* spatial_ctx = (const float*)d_in[2];
    const int*   box_im_ids  = (const int*)d_in[4];
    const float* w_fc   = (const float*)d_in[5];
    const float* b_fc   = (const float*)d_in[6];
    const float* w_ih_f = (const float*)d_in[7];
    const float* w_hh_f = (const float*)d_in[8];
    const float* b_ih_f = (const float*)d_in[9];
    const float* b_hh_f = (const float*)d_in[10];
    const float* w_ih_r = (const float*)d_in[11];
    const float* w_hh_r = (const float*)d_in[12];
    const float* b_ih_r = (const float*)d_in[13];
    const float* b_hh_r = (const float*)d_in[14];

    float* ws   = (float*)d_ws;
    float* x    = ws;                       // phase-1 use of region A
    float* part = ws + 1613824;             // phase-1 use of region A
    float* wPT  = ws;                       // phase-2 use of region A (32 MB)
    float* xg   = ws + 8388608;             // 2*512*4096 = 4194304
    float* h_T  = ws + 12582912;            // 2 phases * 32768
    float* c_T  = h_T + 65536;              // 32768
    float* hsum = c_T + 32768;              // 32768

    float* out = (float*)d_out;
    float* emb = out + 32768;               // second output region, also LSTM input

    build_x<<<2048, 256, 0, stream>>>(boxes_ext, box_feats, spatial_ctx, box_im_ids, x);
    gemm_emb_part<<<dim3(8, 16, 8), 64, 0, stream>>>(x, w_fc, part);
    reduce_emb<<<2048, 256, 0, stream>>>(part, b_fc, emb);
    // region A is now dead -> safe to overwrite with wPT
    transpose_whh<<<dim3(16, 64, 2), 256, 0, stream>>>(w_hh_f, w_hh_r, wPT);
    gemm_xg<<<dim3(8, 128), 64, 0, stream>>>(emb, w_ih_f, w_ih_r,
                                             b_ih_f, b_hh_f, b_ih_r, b_hh_r, xg);
    hipMemsetAsync(h_T, 0, (size_t)(65536 + 32768 + 32768) * sizeof(float), stream);
    for (int s = 0; s < TT; ++s) {
        float* hin  = h_T + (s & 1) * 32768;
        float* hout = h_T + ((s + 1) & 1) * 32768;
        lstm_step<<<256, 256, 0, stream>>>(wPT, xg, hin, hout, c_T, hsum, s);
    }
    finalize_ctx<<<128, 256, 0, stream>>>(hsum, out);
}